// Round 4
// baseline (12301.022 us; speedup 1.0000x reference)
//
#include <hip/hip_runtime.h>

typedef unsigned short u16;
typedef unsigned int u32;
typedef short short8 __attribute__((ext_vector_type(8)));
typedef float floatx4 __attribute__((ext_vector_type(4)));
typedef u32 u32x4 __attribute__((ext_vector_type(4)));

#define SLEN 2048
#define BATCH 64
#define FDIM 512
#define HDIM 512
#define NWG 128
#define NTH 512                        // 8 waves: 0-3 recurrent K-slices, 4-7 x gates
#define GROUPS 4
#define ROWS 16                        // batch rows per group
#define HROW_U32 (HDIM/2)              // 256 u32 per h row
#define HGRP_U32 (ROWS*HROW_U32)       // 4096 u32 per group
#define HB_U32 (GROUPS*HGRP_U32)       // 16384 u32 per ring slot
#define NRING 4
#define WS_BYTES (NRING*HB_U32*4)      // 256 KiB h ring
#define SENT 0xFFFFFFFFu               // bf16 NaN-pair: unreachable for real h

#define XSLOTS 8
#define TILE_F (16*20)                 // padded col-major 16x16 f32 tile
#define SCRH_F (16*TILE_F)             // 16 tiles: 4 K-waves x 4 gates
#define SCRX_SLOT_F (4*TILE_F)         // 4 gate tiles per slot
#define SCRX_F (XSLOTS*SCRX_SLOT_F)

#define ARENA_BYTES 131072
// phase 1: [0,64K) wh staging, [64K,128K) wx staging
// phase 2: scr_h [0,20480), scr_x [20480,61440), flags [61440,61504)
#define OFF_SCRX (SCRH_F*4)
#define OFF_FLAGS (OFF_SCRX + SCRX_F*4)
// flags: [0..3]=tiles-written(done) [4..7]=xready [8..11]=xconsumed [12..15]=tiles-read(rdone)

// fp32 -> bf16 round-to-nearest-even
__device__ __forceinline__ u16 f2bf_rne(float f) {
  union { float f; u32 u; } v; v.f = f;
  u32 u = v.u + 0x7FFFu + ((v.u >> 16) & 1u);
  return (u16)(u >> 16);
}
__device__ __forceinline__ float sigmoidf_fast(float x) {
  return 1.0f / (1.0f + __expf(-x));
}
__device__ __forceinline__ float tanhf_fast(float x) {
  return 1.0f - 2.0f / (__expf(2.0f * x) + 1.0f);
}

// Persistent grouped LSTM, weights-in-VGPR, K-split recurrent waves, no in-loop barrier.
// WG (g = bid&3, c = bid>>2): batches [g*16,+16), h-cols [c*16,+16).
__global__ __launch_bounds__(NTH, 1)
void lstm_persistent(
    const float* __restrict__ x,
    const float* __restrict__ w_ii, const float* __restrict__ b_ii,
    const float* __restrict__ w_hi, const float* __restrict__ b_hi,
    const float* __restrict__ w_if, const float* __restrict__ b_if,
    const float* __restrict__ w_hf, const float* __restrict__ b_hf,
    const float* __restrict__ w_ig, const float* __restrict__ b_ig,
    const float* __restrict__ w_hg, const float* __restrict__ b_hg,
    const float* __restrict__ w_io, const float* __restrict__ b_io,
    const float* __restrict__ w_ho, const float* __restrict__ b_ho,
    float* __restrict__ out, u32* __restrict__ hbuf)
{
  __shared__ __align__(16) char arena[ARENA_BYTES];

  const int tid  = threadIdx.x;
  const int g    = blockIdx.x & 3;
  const int c    = blockIdx.x >> 2;
  const int wv   = tid >> 6;
  const int lane = tid & 63;
  const int n    = lane & 15;     // batch row (A-frag) / h-col (B/D-frag, epilogue)
  const int kq   = lane >> 4;

  u16* lds_wh = (u16*)arena;
  u16* lds_wx = (u16*)(arena + 65536);

  // ---- phase 1: stage weights fp32->bf16 in MFMA B-frag order ----
  {
    const float* WH[4] = {w_hi, w_hf, w_hg, w_ho};
    const float* WX[4] = {w_ii, w_if, w_ig, w_io};
    for (int idx = tid; idx < 4*512*16; idx += NTH) {
      int col = idx & 15;
      int k   = (idx >> 4) & 511;
      int gt  = idx >> 13;
      int kk  = k >> 5, rem = k & 31, quad = rem >> 3, j = rem & 7;
      int di  = ((gt*16 + kk)*64 + quad*16 + col)*8 + j;
      int src = k*HDIM + c*16 + col;
      lds_wh[di] = f2bf_rne(WH[gt][src]);
      lds_wx[di] = f2bf_rne(WX[gt][src]);
    }
  }
  __syncthreads();

  // ---- extract per-wave weight fragments into VGPRs ----
  short8 wf[16];
  if (wv < 4) {
    // rec wave wv: wf[gt*4+kkl] = Wh frag, gate gt, kk = wv*4+kkl (K-slice [128*wv,+128))
#pragma unroll
    for (int gt = 0; gt < 4; ++gt)
#pragma unroll
      for (int kkl = 0; kkl < 4; ++kkl)
        wf[gt*4 + kkl] = *(const short8*)&lds_wh[((gt*16 + wv*4 + kkl)*64 + lane)*8];
  } else {
    const int gt = wv - 4;
#pragma unroll
    for (int kk = 0; kk < 16; ++kk)
      wf[kk] = *(const short8*)&lds_wx[((gt*16 + kk)*64 + lane)*8];
  }
  __syncthreads();   // frags in VGPR; arena reusable

  float* scr_h = (float*)arena;
  float* scr_x = (float*)(arena + OFF_SCRX);
  int*   flg   = (int*)(arena + OFF_FLAGS);
  if (tid < 16) flg[tid] = -1;
  __syncthreads();

  if (wv < 4) {
    // ================== recurrent K-slice wave ==================
    const int w     = wv;
    const int row_e = w*4 + kq;          // epilogue row (this lane's state row)
    const int colg  = c*16 + n;          // epilogue col
    const float b0 = b_ii[colg] + b_hi[colg];
    const float b1 = b_if[colg] + b_hf[colg];
    const float b2 = b_ig[colg] + b_hg[colg];
    const float b3 = b_io[colg] + b_ho[colg];
    float c_st = 0.f;

    for (int t = 0; t < SLEN; ++t) {
      floatx4 a0 = {0.f,0.f,0.f,0.f}, a1 = {0.f,0.f,0.f,0.f};
      floatx4 a2 = {0.f,0.f,0.f,0.f}, a3 = {0.f,0.f,0.f,0.f};

      if (t > 0) {
        // poll own 4KB K-slice of ring[t&3]: 4 dwordx4/lane, sentinel retry
        const u32* hp = hbuf + (size_t)(t & 3)*HB_U32 + g*HGRP_U32
                      + n*HROW_U32 + w*64 + kq*4;
        u32x4 hv0, hv1, hv2, hv3;
        int ready;
        do {
          asm volatile("global_load_dwordx4 %0, %1, off sc0 sc1"            : "=v"(hv0) : "v"(hp));
          asm volatile("global_load_dwordx4 %0, %1, off offset:64 sc0 sc1"  : "=v"(hv1) : "v"(hp));
          asm volatile("global_load_dwordx4 %0, %1, off offset:128 sc0 sc1" : "=v"(hv2) : "v"(hp));
          asm volatile("global_load_dwordx4 %0, %1, off offset:192 sc0 sc1" : "=v"(hv3) : "v"(hp));
          asm volatile("s_waitcnt vmcnt(0)" ::: "memory");
          __builtin_amdgcn_sched_barrier(0);
          u32 mx = 0u;
#pragma unroll
          for (int j = 0; j < 4; ++j) {
            mx = hv0[j] > mx ? hv0[j] : mx;
            mx = hv1[j] > mx ? hv1[j] : mx;
            mx = hv2[j] > mx ? hv2[j] : mx;
            mx = hv3[j] > mx ? hv3[j] : mx;
          }
          ready = __all((int)(mx != SENT));
        } while (!ready);

        union { u32x4 u; short8 s; } h0, h1, h2, h3;
        h0.u = hv0; h1.u = hv1; h2.u = hv2; h3.u = hv3;
        a0 = __builtin_amdgcn_mfma_f32_16x16x32_bf16(h0.s, wf[0],  a0, 0,0,0);
        a1 = __builtin_amdgcn_mfma_f32_16x16x32_bf16(h0.s, wf[4],  a1, 0,0,0);
        a2 = __builtin_amdgcn_mfma_f32_16x16x32_bf16(h0.s, wf[8],  a2, 0,0,0);
        a3 = __builtin_amdgcn_mfma_f32_16x16x32_bf16(h0.s, wf[12], a3, 0,0,0);
        a0 = __builtin_amdgcn_mfma_f32_16x16x32_bf16(h1.s, wf[1],  a0, 0,0,0);
        a1 = __builtin_amdgcn_mfma_f32_16x16x32_bf16(h1.s, wf[5],  a1, 0,0,0);
        a2 = __builtin_amdgcn_mfma_f32_16x16x32_bf16(h1.s, wf[9],  a2, 0,0,0);
        a3 = __builtin_amdgcn_mfma_f32_16x16x32_bf16(h1.s, wf[13], a3, 0,0,0);
        a0 = __builtin_amdgcn_mfma_f32_16x16x32_bf16(h2.s, wf[2],  a0, 0,0,0);
        a1 = __builtin_amdgcn_mfma_f32_16x16x32_bf16(h2.s, wf[6],  a1, 0,0,0);
        a2 = __builtin_amdgcn_mfma_f32_16x16x32_bf16(h2.s, wf[10], a2, 0,0,0);
        a3 = __builtin_amdgcn_mfma_f32_16x16x32_bf16(h2.s, wf[14], a3, 0,0,0);
        a0 = __builtin_amdgcn_mfma_f32_16x16x32_bf16(h3.s, wf[3],  a0, 0,0,0);
        a1 = __builtin_amdgcn_mfma_f32_16x16x32_bf16(h3.s, wf[7],  a1, 0,0,0);
        a2 = __builtin_amdgcn_mfma_f32_16x16x32_bf16(h3.s, wf[11], a2, 0,0,0);
        a3 = __builtin_amdgcn_mfma_f32_16x16x32_bf16(h3.s, wf[15], a3, 0,0,0);
      }

      // tile WAW guard: all waves must have READ step t-1 tiles
#pragma unroll
      for (int i = 0; i < 4; ++i)
        while (__hip_atomic_load(&flg[12+i], __ATOMIC_RELAXED, __HIP_MEMORY_SCOPE_WORKGROUP) < t-1) {}
      asm volatile("" ::: "memory");

      // write partial tiles (col-major [col][row], D: col=n, row=kq*4+r)
      *(floatx4*)&scr_h[((w*4 + 0)*16 + n)*20 + kq*4] = a0;
      *(floatx4*)&scr_h[((w*4 + 1)*16 + n)*20 + kq*4] = a1;
      *(floatx4*)&scr_h[((w*4 + 2)*16 + n)*20 + kq*4] = a2;
      *(floatx4*)&scr_h[((w*4 + 3)*16 + n)*20 + kq*4] = a3;
      asm volatile("s_waitcnt lgkmcnt(0)" ::: "memory");
      __hip_atomic_store(&flg[w], t, __ATOMIC_RELAXED, __HIP_MEMORY_SCOPE_WORKGROUP);

      // join: all K-partials written, this step's x tiles ready
#pragma unroll
      for (int i = 0; i < 4; ++i)
        while (__hip_atomic_load(&flg[i], __ATOMIC_RELAXED, __HIP_MEMORY_SCOPE_WORKGROUP) < t) {}
#pragma unroll
      for (int i = 0; i < 4; ++i)
        while (__hip_atomic_load(&flg[4+i], __ATOMIC_RELAXED, __HIP_MEMORY_SCOPE_WORKGROUP) < t) {}
      asm volatile("" ::: "memory");

      // re-arm ring[(t-1)&3]: own rows, own col-block (drained by vmcnt(0) below
      // before this step's h becomes visible => no stale/clobber races)
      if (t > 0 && lane < 32) {
        int rr = w*4 + (lane >> 3);
        int wd = lane & 7;
        __hip_atomic_store(&hbuf[(size_t)((t-1) & 3)*HB_U32 + g*HGRP_U32
                                 + rr*HROW_U32 + c*8 + wd],
                           SENT, __ATOMIC_RELAXED, __HIP_MEMORY_SCOPE_AGENT);
      }

      // epilogue: sum 4 K-partials per gate for (row_e, n)
      float s0 = 0.f, s1 = 0.f, s2 = 0.f, s3 = 0.f;
#pragma unroll
      for (int w2 = 0; w2 < 4; ++w2) {
        s0 += scr_h[((w2*4 + 0)*16 + n)*20 + row_e];
        s1 += scr_h[((w2*4 + 1)*16 + n)*20 + row_e];
        s2 += scr_h[((w2*4 + 2)*16 + n)*20 + row_e];
        s3 += scr_h[((w2*4 + 3)*16 + n)*20 + row_e];
      }
      const float* sxp = scr_x + (size_t)(t & 7)*SCRX_SLOT_F;
      float x0 = sxp[(0*16 + n)*20 + row_e];
      float x1 = sxp[(1*16 + n)*20 + row_e];
      float x2 = sxp[(2*16 + n)*20 + row_e];
      float x3 = sxp[(3*16 + n)*20 + row_e];

      float gi = sigmoidf_fast(s0 + x0 + b0);
      float gf = sigmoidf_fast(s1 + x1 + b1);
      float gg = tanhf_fast  (s2 + x2 + b2);
      float go = sigmoidf_fast(s3 + x3 + b3);
      c_st = gf * c_st + gi * gg;
      float h_new = go * tanhf_fast(c_st);

      if (t == SLEN - 1) {
        int row = g*ROWS + row_e;
        out[row*HDIM + colg]              = h_new;
        out[BATCH*HDIM + row*HDIM + colg] = c_st;
      } else {
        u32 hb = (u32)f2bf_rne(h_new);
        u32 o  = (u32)__shfl_xor((int)hb, 1);
        asm volatile("s_waitcnt vmcnt(0)" ::: "memory");   // resets acked before h visible
        if ((n & 1) == 0) {
          u32 val = (o << 16) | hb;
          __hip_atomic_store(&hbuf[(size_t)((t+1) & 3)*HB_U32 + g*HGRP_U32
                                   + row_e*HROW_U32 + c*8 + (n >> 1)],
                             val, __ATOMIC_RELAXED, __HIP_MEMORY_SCOPE_AGENT);
        }
      }

      // release: x slot consumed, tiles read
      asm volatile("" ::: "memory");
      __hip_atomic_store(&flg[8+w],  t, __ATOMIC_RELAXED, __HIP_MEMORY_SCOPE_WORKGROUP);
      __hip_atomic_store(&flg[12+w], t, __ATOMIC_RELAXED, __HIP_MEMORY_SCOPE_WORKGROUP);
    }
  } else {
    // ================== x-projection wave (one gate, full K) ==================
    const int gt = wv - 4;
    const float* xbase = x + (size_t)(g*ROWS + n) * (SLEN * FDIM);

    for (int u = 0; u < SLEN; ++u) {
      if (u >= XSLOTS) {
        const int lim = u - XSLOTS;
#pragma unroll
        for (int i = 0; i < 4; ++i)
          while (__hip_atomic_load(&flg[8+i], __ATOMIC_RELAXED, __HIP_MEMORY_SCOPE_WORKGROUP) < lim) {}
        asm volatile("" ::: "memory");
      }
      const float* xrow = xbase + (size_t)u * FDIM;
      floatx4 acc = {0.f,0.f,0.f,0.f};
#pragma unroll
      for (int kk = 0; kk < 16; ++kk) {
        floatx4 xa = *(const floatx4*)(xrow + kk*32 + kq*8);
        floatx4 xb = *(const floatx4*)(xrow + kk*32 + kq*8 + 4);
        short8 ax;
#pragma unroll
        for (int j = 0; j < 4; ++j) {
          ax[j]     = (short)f2bf_rne(xa[j]);
          ax[4 + j] = (short)f2bf_rne(xb[j]);
        }
        acc = __builtin_amdgcn_mfma_f32_16x16x32_bf16(ax, wf[kk], acc, 0, 0, 0);
      }
      *(floatx4*)&scr_x[(size_t)(u & 7)*SCRX_SLOT_F + (gt*16 + n)*20 + kq*4] = acc;
      asm volatile("s_waitcnt lgkmcnt(0)" ::: "memory");
      __hip_atomic_store(&flg[4+gt], u, __ATOMIC_RELAXED, __HIP_MEMORY_SCOPE_WORKGROUP);
    }
  }
}

extern "C" void kernel_launch(void* const* d_in, const int* in_sizes, int n_in,
                              void* d_out, int out_size, void* d_ws, size_t ws_size,
                              hipStream_t stream) {
  (void)in_sizes; (void)n_in; (void)out_size; (void)ws_size;
  // ws: 4-ring h buffer (u32-packed bf16, [ring][group][row][256]) -- sentinel-armed
  u32* hbuf = (u32*)d_ws;
  (void)hipMemsetAsync(d_ws, 0xFF, WS_BYTES, stream);

  lstm_persistent<<<dim3(NWG), dim3(NTH), 0, stream>>>(
      (const float*)d_in[0],
      (const float*)d_in[1],  (const float*)d_in[2],   // w_ii, b_ii
      (const float*)d_in[3],  (const float*)d_in[4],   // w_hi, b_hi
      (const float*)d_in[5],  (const float*)d_in[6],   // w_if_, b_if_
      (const float*)d_in[7],  (const float*)d_in[8],   // w_hf, b_hf
      (const float*)d_in[9],  (const float*)d_in[10],  // w_ig, b_ig
      (const float*)d_in[11], (const float*)d_in[12],  // w_hg, b_hg
      (const float*)d_in[13], (const float*)d_in[14],  // w_io, b_io
      (const float*)d_in[15], (const float*)d_in[16],  // w_ho, b_ho
      (float*)d_out, hbuf);
}